// Round 5
// baseline (452.531 us; speedup 1.0000x reference)
//
#include <hip/hip_runtime.h>
#include <stdint.h>

// Problem constants
#define B 2048
#define S 201
#define HALF 100                 // S/2
#define D 128
#define BS (B * S)               // 411648
#define OFF_POS (BS * D)         // 52690944  : pos_enc starts here (floats)
#define OFF_VT  (2 * OFF_POS)    // 105381888 : visited_time (floats)
#define OFF_T2  (OFF_VT + BS)    // 105793536 : top2 (floats, 2 per bs)
#define F4B (S * (D / 4))        // 6432      : float4 elements per batch in [B,S,D]
#define TPB 256

typedef float vf4 __attribute__((ext_vector_type(4)));
typedef float vf2 __attribute__((ext_vector_type(2)));

// ROUND 5 (single variable vs round 4): per-wave CONTIGUOUS write ranges.
// All previous variants striped waves through the batch chunk (idx4 += 192/256),
// so each wave stored 1 KB then jumped 3-4 KB; a block's 100 KB window was
// filled by 3-4 drifting interleaved streams. The rocclr fill — the only
// kernel observed at 6.2 TB/s on this buffer — writes linearly per wave.
// Here wave w owns one contiguous sub-range (inner stride 64 lanes*16B = 1 KB),
// so consecutive store instructions from a wave write consecutive 1 KB chunks.
// Theory: HBM write row-locality is the ~90 us residual (2.7 vs 6.2 TB/s).
__global__ __launch_bounds__(TPB, 8) void fused(const float* __restrict__ x,
                                                const int* __restrict__ sol,
                                                const float* __restrict__ W,
                                                const float* __restrict__ pattern,
                                                float* __restrict__ out) {
    __shared__ uint8_t s_sol[S];
    __shared__ uint8_t s_vis[S];

    const int tid  = threadIdx.x;
    const int lane = tid & 63;
    const int b    = blockIdx.x;

    if (tid < 64) {
        // wave 0: stage sol (coalesced), then lane 0 runs the bare chase.
        for (int j = tid; j < S; j += 64)
            s_sol[j] = (uint8_t)sol[b * S + j];
        // wave-0 DS writes complete before lane 0's reads (same-wave, in-order DS)
        asm volatile("s_waitcnt lgkmcnt(0)" ::: "memory");
        if (tid == 0) {
            int pre = 0;
            #pragma unroll 1
            for (int i = 0; i < S; ++i) {
                int cur = s_sol[pre];          // the ONLY serial dependence
                s_vis[cur] = (uint8_t)(i + 1); // every node visited exactly once
                pre = cur;
            }
        }
    } else {
        // waves 1-3: x_embedding, each wave a LINEAR 2144-f4 (33.5 KB) range
        const int w = (tid >> 6) - 1;     // 0..2
        const float4* W4 = (const float4*)W;
        const float2* x2 = (const float2*)x + b * S;
        vf4* o4 = (vf4*)out + b * F4B;
        const int start = w * 2144;       // 3*2144 = 6432 = F4B
        const int end   = start + 2144;
        for (int idx4 = start + lane; idx4 < end; idx4 += 64) {
            const int d4 = idx4 & 31;
            float4 w0 = W4[d4 * 2];       // {W[4d4][0],W[4d4][1],W[4d4+1][0],W[4d4+1][1]}
            float4 w1 = W4[d4 * 2 + 1];
            float2 xv = x2[idx4 >> 5];
            vf4 o;
            o.x = xv.x * w0.x + xv.y * w0.y;
            o.y = xv.x * w0.z + xv.y * w0.w;
            o.z = xv.x * w1.x + xv.y * w1.y;
            o.w = xv.x * w1.z + xv.y * w1.w;
            o4[idx4] = o;
        }
    }
    __syncthreads();

    // P2a: per-node top2 (parallel scan over vis[]) + vt/top2 dumps.
    // s_vis reads in the q-loop are wave-uniform -> broadcast, conflict-free.
    for (int c = tid; c < S; c += TPB) {
        int t = s_vis[c];                  // t = vis[c] in 1..201
        int best = 0, bi = 0, sec = -1, si = 1;  // {0.0@0} seed; -1 ~ -0.01
        #pragma unroll 4
        for (int q = 1; q <= HALF; ++q) {
            int vp = s_vis[q];
            int vd = s_vis[q + HALF];
            bool open = (vp <= t) && !((vp < vd) && (vd <= t));
            int v = open ? vp : -1;
            if (v > best) { sec = best; si = bi; best = v; bi = q; }
            else if (v > sec) { sec = v; si = q; }
        }
        out[OFF_VT + b * S + c] = (float)t;
        vf2 f2 = { (float)bi, (float)si };
        ((vf2*)(out + OFF_T2))[b * S + c] = f2;
    }

    // P2b: pos_enc, each wave a LINEAR 1608-f4 (25.1 KB) range
    {
        const vf4* p4 = (const vf4*)pattern;
        vf4* o4 = (vf4*)(out + OFF_POS) + b * F4B;
        const int wv    = tid >> 6;        // 0..3
        const int start = wv * 1608;       // 4*1608 = 6432 = F4B
        const int end   = start + 1608;
        for (int idx4 = start + lane; idx4 < end; idx4 += 64) {
            int vt  = s_vis[idx4 >> 5];            // 1..201 (broadcast read)
            int row = (vt >= S) ? (vt - S) : vt;   // vt % S
            o4[idx4] = p4[row * 32 + (idx4 & 31)];
        }
    }
}

extern "C" void kernel_launch(void* const* d_in, const int* in_sizes, int n_in,
                              void* d_out, int out_size, void* d_ws, size_t ws_size,
                              hipStream_t stream) {
    const float* x       = (const float*)d_in[0];   // [2048,201,2] f32
    const int*   sol     = (const int*)d_in[1];     // [2048,201] int
    const float* W       = (const float*)d_in[2];   // [128,2] f32
    const float* pattern = (const float*)d_in[3];   // [201,128] f32
    float* out = (float*)d_out;

    hipLaunchKernelGGL(fused, dim3(B), dim3(TPB), 0, stream, x, sol, W, pattern, out);
}